// Round 1
// baseline (235.355 us; speedup 1.0000x reference)
//
#include <hip/hip_runtime.h>
#include <hip/hip_bf16.h>
#include <stdint.h>

#define DI __device__ __forceinline__

typedef float f32x4 __attribute__((ext_vector_type(4)));
typedef short bf16x8 __attribute__((ext_vector_type(8)));

constexpr int BB = 8192, TT = 128, DD = 16, HH = 32;
constexpr float kEPS = 1e-5f;
constexpr float kLOG2E = 1.44269504088896340736f;

// ---------------- helpers ----------------
DI float rcpf_(float x) { return __builtin_amdgcn_rcpf(x); }
DI float exp2f_(float x) { return __builtin_amdgcn_exp2f(x); }
// acc already = -u*log2e  ->  sigmoid(u)
DI float sig_pre(float acc) { return rcpf_(1.0f + exp2f_(acc)); }
// plain sigmoid(x)
DI float sigm(float x) { return rcpf_(1.0f + exp2f_(-kLOG2E * x)); }

DI uint32_t cvtpk(float lo, float hi) {
  uint32_t r;
  asm("v_cvt_pk_bf16_f32 %0, %1, %2" : "=v"(r) : "v"(lo), "v"(hi));
  return r;
}

DI f32x4 mfma_(bf16x8 a, bf16x8 b, f32x4 c) {
  return __builtin_amdgcn_mfma_f32_16x16x32_bf16(a, b, c, 0, 0, 0);
}

// C-layout f32 h[8] (h[t2*4+r] = value at (row=4*kg+r, col=c+16*t2)) ->
// bf16 A-fragment via wave-private LDS tile. Row stride 72 ushorts (144 B)
// to spread banks; k-permuted layout: physical slot 2c   = logical col c,
//                                     physical slot 2c+1 = logical col c+16.
DI bf16x8 toFrag(uint16_t* buf, const float h[8], int c, int kg) {
#pragma unroll
  for (int r = 0; r < 4; ++r) {
    uint32_t pk = cvtpk(h[r], h[4 + r]);
    *(uint32_t*)(buf + (4 * kg + r) * 72 + 2 * c) = pk;
  }
  asm volatile("s_waitcnt lgkmcnt(0)" ::: "memory");
  return *(const bf16x8*)(buf + c * 72 + kg * 8);
}

// GRU cell, pre-scaled weights: rz rows by -log2e, n rows by +2log2e.
DI void gru(bf16x8 xf, bf16x8 hf, const bf16x8 Wih[6], const bf16x8 Whh[6],
            const float brz[4], const float bin[2], const float bhn[2],
            float h[8]) {
  f32x4 zero = {0.f, 0.f, 0.f, 0.f};
  f32x4 rz0 = zero, rz1 = zero, rz2 = zero, rz3 = zero;
  rz0 = mfma_(xf, Wih[0], rz0); rz0 = mfma_(hf, Whh[0], rz0);
  rz1 = mfma_(xf, Wih[1], rz1); rz1 = mfma_(hf, Whh[1], rz1);
  rz2 = mfma_(xf, Wih[2], rz2); rz2 = mfma_(hf, Whh[2], rz2);
  rz3 = mfma_(xf, Wih[3], rz3); rz3 = mfma_(hf, Whh[3], rz3);
  f32x4 gi0 = mfma_(xf, Wih[4], zero), gi1 = mfma_(xf, Wih[5], zero);
  f32x4 gh0 = mfma_(hf, Whh[4], zero), gh1 = mfma_(hf, Whh[5], zero);
#pragma unroll
  for (int r = 0; r < 4; ++r) {
    float rg0 = sig_pre(rz0[r] + brz[0]);
    float rg1 = sig_pre(rz1[r] + brz[1]);
    float zg0 = sig_pre(rz2[r] + brz[2]);
    float zg1 = sig_pre(rz3[r] + brz[3]);
    float w0 = gi0[r] + bin[0] + rg0 * (gh0[r] + bhn[0]);
    float w1 = gi1[r] + bin[1] + rg1 * (gh1[r] + bhn[1]);
    float n0 = 1.0f - 2.0f * rcpf_(1.0f + exp2f_(w0));
    float n1 = 1.0f - 2.0f * rcpf_(1.0f + exp2f_(w1));
    h[r]     = n0 + zg0 * (h[r] - n0);
    h[4 + r] = n1 + zg1 * (h[4 + r] - n1);
  }
}

// ---------------- weight prep (per net) ----------------
// ws per-net block (64 KiB stride), bf16 area (uint16 offsets):
//   0: Wih0[96][32]  3072: Whh0  6144: Wih1  9216: Whh1
//   12288: embW[32][32] (BN-folded)  13312: outW[16][32] (zero-padded)
// f32 bias area at byte 28672: brz0[64] bin0[32] bhn0[32]
//   brz1[64] bin1[32] bhn1[32] bias_e[32] outB[16]
__global__ void prep_net(const float* Wih0, const float* Whh0,
                         const float* bih0, const float* bhh0,
                         const float* Wih1, const float* Whh1,
                         const float* bih1, const float* bhh1,
                         const float* embW, const float* embB,
                         const float* bng, const float* bnb,
                         const float* bnm, const float* bnv,
                         const float* outW, const float* outB,
                         int outDim, uint8_t* wsbase) {
  int tid = threadIdx.x;
  uint16_t* W = (uint16_t*)wsbase;
  float* bias = (float*)(wsbase + 28672);
  auto cvt = [](float f) -> uint16_t {
    union { float f; uint32_t u; } v; v.f = f;
    uint32_t u = v.u;
    return (uint16_t)((u + 0x7FFF + ((u >> 16) & 1)) >> 16);  // RNE
  };
  const float* srcs[4] = {Wih0, Whh0, Wih1, Whh1};
#pragma unroll
  for (int m = 0; m < 4; ++m) {
    const float* src = srcs[m];
    uint16_t* dst = W + m * 3072;
    for (int idx = tid; idx < 3072; idx += 256) {
      int n = idx >> 5, p = idx & 31;
      int k = (p & 1) ? 16 + (p >> 1) : (p >> 1);
      float s = (n < 64) ? -kLOG2E : 2.0f * kLOG2E;
      dst[idx] = cvt(src[n * 32 + k] * s);
    }
  }
  for (int idx = tid; idx < 1024; idx += 256) {
    int n = idx >> 5, p = idx & 31;
    int k = (p & 1) ? 16 + (p >> 1) : (p >> 1);
    float a = bng[n] * rsqrtf(bnv[n] + kEPS);
    (W + 12288)[idx] = cvt(embW[n * 32 + k] * a);
  }
  for (int idx = tid; idx < 512; idx += 256) {
    int n = idx >> 5, p = idx & 31;
    int k = (p & 1) ? 16 + (p >> 1) : (p >> 1);
    float v = (n < outDim) ? outW[n * 32 + k] : 0.0f;
    (W + 13312)[idx] = cvt(v);
  }
  if (tid < 64) {
    bias[tid]       = (bih0[tid] + bhh0[tid]) * (-kLOG2E);
    bias[128 + tid] = (bih1[tid] + bhh1[tid]) * (-kLOG2E);
  }
  if (tid < 32) {
    bias[64 + tid]  = bih0[64 + tid] * (2.0f * kLOG2E);
    bias[96 + tid]  = bhh0[64 + tid] * (2.0f * kLOG2E);
    bias[192 + tid] = bih1[64 + tid] * (2.0f * kLOG2E);
    bias[224 + tid] = bhh1[64 + tid] * (2.0f * kLOG2E);
    float a = bng[tid] * rsqrtf(bnv[tid] + kEPS);
    bias[256 + tid] = a * embB[tid] + bnb[tid] - bnm[tid] * a;
  }
  if (tid < 16) bias[288 + tid] = (tid < outDim) ? outB[tid] : 0.0f;
}

// ---------------- fused RNN + heads ----------------
__global__ __launch_bounds__(256) void rnn_fused(
    const float* __restrict__ S, const float* __restrict__ gS,
    const float* __restrict__ hp0, const float* __restrict__ hd0,
    const uint8_t* __restrict__ ws, float* __restrict__ out) {
  const int tid = threadIdx.x;
  const int lane = tid & 63, wid = tid >> 6;
  const int net = wid & 1;                       // 0 = price, 1 = delta
  const int b0 = blockIdx.x * 32 + (wid >> 1) * 16;
  const int c = lane & 15, kg = lane >> 4;

  const uint16_t* W = (const uint16_t*)(ws + net * 65536);
  const float* bias = (const float*)(ws + net * 65536 + 28672);

  __shared__ uint16_t lds[4][3][16 * 72];
  uint16_t* buf0 = &lds[wid][0][0];
  uint16_t* buf1 = &lds[wid][1][0];
  uint16_t* buf2 = &lds[wid][2][0];

  // B-fragments: lane holds W[n0 + c][kg*8 .. +8] (k already permuted)
  bf16x8 Wih0f[6], Whh0f[6], Wih1f[6], Whh1f[6], Wembf[2], Woutf;
#pragma unroll
  for (int tt = 0; tt < 6; ++tt) {
    Wih0f[tt] = *(const bf16x8*)(W +         (tt * 16 + c) * 32 + kg * 8);
    Whh0f[tt] = *(const bf16x8*)(W + 3072  + (tt * 16 + c) * 32 + kg * 8);
    Wih1f[tt] = *(const bf16x8*)(W + 6144  + (tt * 16 + c) * 32 + kg * 8);
    Whh1f[tt] = *(const bf16x8*)(W + 9216  + (tt * 16 + c) * 32 + kg * 8);
  }
#pragma unroll
  for (int tt = 0; tt < 2; ++tt)
    Wembf[tt] = *(const bf16x8*)(W + 12288 + (tt * 16 + c) * 32 + kg * 8);
  Woutf = *(const bf16x8*)(W + 13312 + c * 32 + kg * 8);

  float brz0v[4], brz1v[4], bin0v[2], bhn0v[2], bin1v[2], bhn1v[2], bev[2];
#pragma unroll
  for (int i = 0; i < 4; ++i) {
    brz0v[i] = bias[i * 16 + c];
    brz1v[i] = bias[128 + i * 16 + c];
  }
#pragma unroll
  for (int i = 0; i < 2; ++i) {
    bin0v[i] = bias[64 + i * 16 + c];  bhn0v[i] = bias[96 + i * 16 + c];
    bin1v[i] = bias[192 + i * 16 + c]; bhn1v[i] = bias[224 + i * 16 + c];
    bev[i]   = bias[256 + i * 16 + c];
  }
  const float outbv = bias[288 + c];

  // initial hidden states, fp32 C-layout
  const float* hsrc = net ? hd0 : hp0;
  float h0r[8], h1r[8];
#pragma unroll
  for (int t2 = 0; t2 < 2; ++t2)
#pragma unroll
    for (int r = 0; r < 4; ++r) {
      int row = b0 + 4 * kg + r, col = c + 16 * t2;
      h0r[t2 * 4 + r] = hsrc[(size_t)row * HH + col];
      h1r[t2 * 4 + r] = hsrc[((size_t)BB + row) * HH + col];
    }
  bf16x8 h0f = toFrag(buf0, h0r, c, kg);
  bf16x8 h1f = toFrag(buf1, h1r, c, kg);

  // per-lane streaming pointers (walk t downward)
  const float* Sp  = S  + ((size_t)(b0 + c) * TT + (TT - 1)) * DD + kg * 4;
  const float* gSp = gS + (size_t)(b0 + c) * TT + (TT - 1);
  float* po = out + (size_t)(b0 + 4 * kg) * TT + (TT - 1);
  float* od = out + (size_t)BB * TT +
              ((size_t)(b0 + 4 * kg) * TT + (TT - 1)) * DD + c;

  f32x4 sv = *(const f32x4*)Sp;
  float gs = *gSp;

#pragma unroll 1
  for (int t = TT - 1; t >= 0; --t) {
    // prefetch next timestep's x
    const float* Spn  = t ? Sp - DD : Sp;
    const float* gSpn = t ? gSp - 1 : gSp;
    f32x4 svn = *(const f32x4*)Spn;
    float gsn = *gSpn;

    // x fragment: even slots = S[4kg+j], odd slots = g_S (k-permuted layout)
    union { uint32_t u[4]; bf16x8 v; } xu;
    xu.u[0] = cvtpk(sv[0], gs); xu.u[1] = cvtpk(sv[1], gs);
    xu.u[2] = cvtpk(sv[2], gs); xu.u[3] = cvtpk(sv[3], gs);
    bf16x8 xf = xu.v;

    gru(xf, h0f, Wih0f, Whh0f, brz0v, bin0v, bhn0v, h0r);
    h0f = toFrag(buf0, h0r, c, kg);
    gru(h0f, h1f, Wih1f, Whh1f, brz1v, bin1v, bhn1v, h1r);
    h1f = toFrag(buf1, h1r, c, kg);

    // head: e = h1 @ embW^T (BN folded), SiLU, out
    f32x4 zero = {0.f, 0.f, 0.f, 0.f};
    f32x4 e0 = mfma_(h1f, Wembf[0], zero);
    f32x4 e1 = mfma_(h1f, Wembf[1], zero);
    float es[8];
#pragma unroll
    for (int r = 0; r < 4; ++r) {
      float a = e0[r] + bev[0], b = e1[r] + bev[1];
      es[r]     = a * sigm(a);
      es[4 + r] = b * sigm(b);
    }
    bf16x8 ef = toFrag(buf2, es, c, kg);
    f32x4 o = mfma_(ef, Woutf, zero);

    if (net == 0) {
      if (c == 0) {
#pragma unroll
        for (int r = 0; r < 4; ++r) po[r * TT] = o[r] + outbv;
      }
    } else {
#pragma unroll
      for (int r = 0; r < 4; ++r) od[(size_t)r * TT * DD] = sigm(o[r] + outbv);
    }

    sv = svn; gs = gsn;
    Sp = Spn; gSp = gSpn;
    po -= 1; od -= DD;
  }
}

// ---------------- launch ----------------
extern "C" void kernel_launch(void* const* d_in, const int* in_sizes, int n_in,
                              void* d_out, int out_size, void* d_ws,
                              size_t ws_size, hipStream_t stream) {
  const float* S   = (const float*)d_in[0];
  const float* gS  = (const float*)d_in[1];
  const float* hp0 = (const float*)d_in[5];
  const float* hd0 = (const float*)d_in[6];
  uint8_t* ws = (uint8_t*)d_ws;

  prep_net<<<1, 256, 0, stream>>>(
      (const float*)d_in[7],  (const float*)d_in[8],  (const float*)d_in[9],
      (const float*)d_in[10], (const float*)d_in[11], (const float*)d_in[12],
      (const float*)d_in[13], (const float*)d_in[14], (const float*)d_in[15],
      (const float*)d_in[16], (const float*)d_in[17], (const float*)d_in[18],
      (const float*)d_in[19], (const float*)d_in[20], (const float*)d_in[21],
      (const float*)d_in[22], 1, ws);
  prep_net<<<1, 256, 0, stream>>>(
      (const float*)d_in[23], (const float*)d_in[24], (const float*)d_in[25],
      (const float*)d_in[26], (const float*)d_in[27], (const float*)d_in[28],
      (const float*)d_in[29], (const float*)d_in[30], (const float*)d_in[31],
      (const float*)d_in[32], (const float*)d_in[33], (const float*)d_in[34],
      (const float*)d_in[35], (const float*)d_in[36], (const float*)d_in[37],
      (const float*)d_in[38], 16, ws + 65536);

  rnn_fused<<<dim3(BB / 32), dim3(256), 0, stream>>>(S, gS, hp0, hd0, ws,
                                                     (float*)d_out);
}